// Round 8
// baseline (51.625 us; speedup 1.0000x reference)
//
#include <hip/hip_runtime.h>
#include <cstdint>

#define IMG_ELEMS 784
#define NIMG_GRP 16
#define IMG_STRIDE_DW 788                    // 197*16B: aligned, odd superbank
#define STAGE_DW (NIMG_GRP * IMG_STRIDE_DW)  // 12,608 dw = 50,432 B per buffer
#define NWAVES 8
#define SCRATCH_DW (NWAVES * 256)            // 8 waves x 64 lanes x 4 f32 = 2048 dw
#define BLOCKS 256                           // 1 block/CU

typedef __attribute__((ext_vector_type(8))) short short8;
typedef __attribute__((ext_vector_type(4))) float f32x4;

union ABu { uint32_t u[4]; short8 v; };

typedef const __attribute__((address_space(1))) void* gp1_t;
typedef __attribute__((address_space(3))) void* lp3_t;

__device__ inline uint32_t pk_bf16(float a, float b) {
    uint32_t r;
    asm("v_cvt_pk_bf16_f32 %0, %1, %2" : "=v"(r) : "v"(a), "v"(b));
    return r;  // lo = bf16(a), hi = bf16(b)
}

// wave `widb` DMA-stages its 2 images of group `grp` into `dst` (f32, coalesced)
// -> exactly 8 vmcnt events per wave per group
__device__ inline void stage_group(const float* __restrict__ x, float* dst,
                                   int grp, int widb, int lane) {
    const float* gsrc = x + (size_t)grp * (NIMG_GRP * IMG_ELEMS);
#pragma unroll
    for (int k = 0; k < 2; ++k) {
        const int im = widb * 2 + k;
        const float* s = gsrc + im * IMG_ELEMS;
        float* d = dst + im * IMG_STRIDE_DW;
#pragma unroll
        for (int j = 0; j < 3; ++j)
            __builtin_amdgcn_global_load_lds((gp1_t)(s + j * 256 + lane * 4),
                                             (lp3_t)(d + j * 256), 16, 0, 0);
        if (lane < 4)
            __builtin_amdgcn_global_load_lds((gp1_t)(s + 768 + lane * 4),
                                             (lp3_t)(d + 768), 16, 0, 0);
    }
}

__global__ __launch_bounds__(512, 1) void fused_digit_dbuf_kernel(
    const float* __restrict__ x,
    const float* __restrict__ cw9,
    const float* __restrict__ Wlin,
    const float* __restrict__ bias,
    float* __restrict__ out,
    int ngroups, int gpb)
{
    __shared__ float smem[2 * STAGE_DW + SCRATCH_DW];
    float* const buf0 = smem;
    float* const buf1 = smem + STAGE_DW;
    float* const scr  = smem + 2 * STAGE_DW;

    const int tid  = threadIdx.x;
    const int lane = tid & 63;
    const int widb = tid >> 6;          // 0..7
    const int rc = lane & 15;           // A-row (image) AND D-col (class)
    const int g  = lane >> 4;           // conv output cols 8g..8g+7

    float cw[9];
#pragma unroll
    for (int k = 0; k < 9; ++k) cw[k] = cw9[k];
    const float bv = (rc < 10) ? bias[rc] : 0.0f;

    // K-split over 8 waves: rows 4,4,3,3,3,3,3,3
    const int R0 = (widb < 2) ? 4 * widb : 8 + 3 * (widb - 2);
    const int RC = (widb < 2) ? 4 : 3;

    // W B-fragments for this wave's conv rows (16 VGPRs)
    ABu bf[4];
#pragma unroll
    for (int rr = 0; rr < 4; ++rr) {
        const int r = R0 + rr;
#pragma unroll
        for (int m = 0; m < 4; ++m) {
            const int c0 = 8 * g + 2 * m;
            const int c1 = c0 + 1;
            const bool v0 = (rr < RC) && (c0 < 26) && (rc < 10);
            const bool v1 = (rr < RC) && (c1 < 26) && (rc < 10);
            const float w0 = v0 ? Wlin[(r * 26 + c0) * 10 + rc] : 0.0f;
            const float w1 = v1 ? Wlin[(r * 26 + c1) * 10 + rc] : 0.0f;
            bf[rr].u[m] = pk_bf16(w0, w1);
        }
    }

    // per-lane col offsets, clamped; duplicate data hits zero B-weights
    const int co0 = 8 * g;
    const int co1 = (8 * g + 4 > 24) ? 24 : 8 * g + 4;
    const int co2 = (8 * g + 8 > 24) ? 24 : 8 * g + 8;

    const int gstart = blockIdx.x * gpb;

    if (gstart < ngroups) stage_group(x, buf0, gstart, widb, lane);

    for (int i = 0; i < gpb; ++i) {
        const int grp = gstart + i;
        if (grp >= ngroups) break;   // block-uniform

        float* const cur = (i & 1) ? buf1 : buf0;
        float* const alt = (i & 1) ? buf0 : buf1;

        // pipeline: issue next group's DMA into alt, then counted-wait for cur
        if (i + 1 < gpb && grp + 1 < ngroups) {
            stage_group(x, alt, grp + 1, widb, lane);
            asm volatile("s_waitcnt vmcnt(8)" ::: "memory");
        } else {
            asm volatile("s_waitcnt vmcnt(0)" ::: "memory");
        }
        __syncthreads();   // all waves' DMA for cur complete

        // ---- conv rows [R0, R0+RC) of image rc, cols 8g..8g+7, f32 ----
        const float* ib = cur + rc * IMG_STRIDE_DW;
        float accr[3][8];
#pragma unroll
        for (int s = 0; s < 3; ++s)
#pragma unroll
            for (int j = 0; j < 8; ++j) accr[s][j] = 0.0f;
        f32x4 acc = {0.f, 0.f, 0.f, 0.f};

#pragma unroll
        for (int t = 0; t < 6; ++t) {          // input rows R0+t, t < RC+2
            if (t < RC + 2) {
                const float* rp = ib + (R0 + t) * 28;
                float in[12];
                *(float4*)&in[0] = *(const float4*)(rp + co0);
                *(float4*)&in[4] = *(const float4*)(rp + co1);
                *(float4*)&in[8] = *(const float4*)(rp + co2);

                const int s0 = t % 3;
                const int s1 = (t + 2) % 3;
                const int s2 = (t + 1) % 3;

                if (t < RC) {
#pragma unroll
                    for (int j = 0; j < 8; ++j)
                        accr[s0][j] = fmaf(in[j], cw[0],
                                      fmaf(in[j + 1], cw[1],
                                      fmaf(in[j + 2], cw[2], accr[s0][j])));
                }
                if (t >= 1 && t <= RC) {
#pragma unroll
                    for (int j = 0; j < 8; ++j)
                        accr[s1][j] = fmaf(in[j], cw[3],
                                      fmaf(in[j + 1], cw[4],
                                      fmaf(in[j + 2], cw[5], accr[s1][j])));
                }
                if (t >= 2) {
#pragma unroll
                    for (int j = 0; j < 8; ++j)
                        accr[s2][j] = fmaf(in[j], cw[6],
                                      fmaf(in[j + 1], cw[7],
                                      fmaf(in[j + 2], cw[8], accr[s2][j])));
                    ABu a;
#pragma unroll
                    for (int m = 0; m < 4; ++m)
                        a.u[m] = pk_bf16(fmaxf(accr[s2][2 * m], 0.f),
                                         fmaxf(accr[s2][2 * m + 1], 0.f));
                    acc = __builtin_amdgcn_mfma_f32_16x16x32_bf16(
                              a.v, bf[t - 2].v, acc, 0, 0, 0);
#pragma unroll
                    for (int j = 0; j < 8; ++j) accr[s2][j] = 0.0f;
                }
            }
        }

        // ---- cross-wave K-reduction ----
        *reinterpret_cast<f32x4*>(scr + widb * 256 + lane * 4) = acc;
        __syncthreads();   // conv reads of cur done + scratch visible

        if (widb == 0) {
            const float* sp = scr + lane * 4;
            float s[4] = {0.f, 0.f, 0.f, 0.f};
#pragma unroll
            for (int w = 0; w < NWAVES; ++w) {
                f32x4 p = *reinterpret_cast<const f32x4*>(sp + w * 256);
#pragma unroll
                for (int q = 0; q < 4; ++q) s[q] += p[q];
            }
            if (rc < 10) {
                float* po = out + ((size_t)grp * NIMG_GRP + (size_t)g * 4) * 10 + rc;
#pragma unroll
                for (int q = 0; q < 4; ++q) po[q * 10] = s[q] + bv;
            }
        }
    }
}

extern "C" void kernel_launch(void* const* d_in, const int* in_sizes, int n_in,
                              void* d_out, int out_size, void* d_ws, size_t ws_size,
                              hipStream_t stream) {
    const float* x   = (const float*)d_in[0];
    const float* cw  = (const float*)d_in[1];
    const float* W   = (const float*)d_in[2];
    const float* b   = (const float*)d_in[3];
    float* out = (float*)d_out;

    const int nimg    = in_sizes[0] / IMG_ELEMS;
    const int ngroups = nimg / NIMG_GRP;
    const int gpb     = (ngroups + BLOCKS - 1) / BLOCKS;  // 16 for B=65536

    hipLaunchKernelGGL(fused_digit_dbuf_kernel, dim3(BLOCKS), dim3(512), 0, stream,
                       x, cw, W, b, out, ngroups, gpb);
}

// Round 9
// 50.467 us; speedup vs baseline: 1.0230x; 1.0230x over previous
//
#include <hip/hip_runtime.h>
#include <cstdint>

#define IMG_ELEMS 784
#define NIMG_GRP 16
#define IMG_STRIDE_DW 788                    // 197*16B: aligned, odd superbank
#define STAGE_DW (NIMG_GRP * IMG_STRIDE_DW)  // 12,608 dw = 50,432 B per buffer
#define NWAVES 8
#define SCRATCH_DW (NWAVES * 256)            // 8 waves x 64 lanes x 4 f32
#define BLOCKS 256                           // 1 block/CU

typedef __attribute__((ext_vector_type(8))) short short8;
typedef __attribute__((ext_vector_type(4))) float f32x4;

union ABu { uint32_t u[4]; short8 v; };

typedef const __attribute__((address_space(1))) void* gp1_t;
typedef __attribute__((address_space(3))) void* lp3_t;

__device__ inline uint32_t pk_bf16(float a, float b) {
    uint32_t r;
    asm("v_cvt_pk_bf16_f32 %0, %1, %2" : "=v"(r) : "v"(a), "v"(b));
    return r;  // lo = bf16(a), hi = bf16(b)
}

// wave `widb` DMA-stages its 2 images of group `grp` (exactly 8 vmcnt events)
__device__ inline void stage_group(const float* __restrict__ x, float* dst,
                                   int grp, int widb, int lane) {
    const float* gsrc = x + (size_t)grp * (NIMG_GRP * IMG_ELEMS);
#pragma unroll
    for (int k = 0; k < 2; ++k) {
        const int im = widb * 2 + k;
        const float* s = gsrc + im * IMG_ELEMS;
        float* d = dst + im * IMG_STRIDE_DW;
#pragma unroll
        for (int j = 0; j < 3; ++j)
            __builtin_amdgcn_global_load_lds((gp1_t)(s + j * 256 + lane * 4),
                                             (lp3_t)(d + j * 256), 16, 0, 0);
        if (lane < 4)
            __builtin_amdgcn_global_load_lds((gp1_t)(s + 768 + lane * 4),
                                             (lp3_t)(d + 768), 16, 0, 0);
    }
}

__global__ __launch_bounds__(512, 1) void fused_digit_pipe_kernel(
    const float* __restrict__ x,
    const float* __restrict__ cw9,
    const float* __restrict__ Wlin,
    const float* __restrict__ bias,
    float* __restrict__ out,
    int ngroups, int gpb)
{
    __shared__ float smem[2 * STAGE_DW + SCRATCH_DW];
    float* const buf0 = smem;
    float* const buf1 = smem + STAGE_DW;
    float* const scr  = smem + 2 * STAGE_DW;

    const int tid  = threadIdx.x;
    const int lane = tid & 63;
    const int widb = tid >> 6;          // 0..7
    const int rc = lane & 15;           // A-row (image) AND D-col (class)
    const int g  = lane >> 4;           // conv output cols 8g..8g+7

    float cw[9];
#pragma unroll
    for (int k = 0; k < 9; ++k) cw[k] = cw9[k];
    const float bv = (rc < 10) ? bias[rc] : 0.0f;

    // K-split over 8 waves: rows 4,4,3,3,3,3,3,3
    const int R0 = (widb < 2) ? 4 * widb : 8 + 3 * (widb - 2);
    const int RC = (widb < 2) ? 4 : 3;

    // W B-fragments for this wave's conv rows (16 VGPRs)
    ABu bf[4];
#pragma unroll
    for (int rr = 0; rr < 4; ++rr) {
        const int r = R0 + rr;
#pragma unroll
        for (int m = 0; m < 4; ++m) {
            const int c0 = 8 * g + 2 * m;
            const int c1 = c0 + 1;
            const bool v0 = (rr < RC) && (c0 < 26) && (rc < 10);
            const bool v1 = (rr < RC) && (c1 < 26) && (rc < 10);
            const float w0 = v0 ? Wlin[(r * 26 + c0) * 10 + rc] : 0.0f;
            const float w1 = v1 ? Wlin[(r * 26 + c1) * 10 + rc] : 0.0f;
            bf[rr].u[m] = pk_bf16(w0, w1);
        }
    }

    // per-lane col offsets, clamped; duplicate data hits zero B-weights
    const int co0 = 8 * g;
    const int co1 = (8 * g + 4 > 24) ? 24 : 8 * g + 4;
    const int co2 = (8 * g + 8 > 24) ? 24 : 8 * g + 8;

    const int gstart = blockIdx.x * gpb;

    if (gstart < ngroups) stage_group(x, buf0, gstart, widb, lane);

    for (int i = 0; i < gpb; ++i) {
        const int grp = gstart + i;
        if (grp >= ngroups) break;   // block-uniform

        float* const cur = (i & 1) ? buf1 : buf0;
        float* const alt = (i & 1) ? buf0 : buf1;

        // issue next group's DMA, then COUNTED wait: group i's 8 loads done,
        // group i+1's 8 loads stay in flight ACROSS the raw barrier (T3/T4)
        if (i + 1 < gpb && grp + 1 < ngroups) {
            stage_group(x, alt, grp + 1, widb, lane);
            asm volatile("s_waitcnt vmcnt(8)" ::: "memory");
        } else {
            asm volatile("s_waitcnt vmcnt(0)" ::: "memory");
        }
        __builtin_amdgcn_s_barrier();        // raw: no compiler vmcnt(0) drain
        __builtin_amdgcn_sched_barrier(0);

        // ---- conv rows [R0, R0+RC) of image rc, cols 8g..8g+7, f32 ----
        const float* ib = cur + rc * IMG_STRIDE_DW;
        float accr[3][8];
#pragma unroll
        for (int s = 0; s < 3; ++s)
#pragma unroll
            for (int j = 0; j < 8; ++j) accr[s][j] = 0.0f;
        f32x4 acc = {0.f, 0.f, 0.f, 0.f};

#pragma unroll
        for (int t = 0; t < 6; ++t) {          // input rows R0+t, t < RC+2
            if (t < RC + 2) {
                const float* rp = ib + (R0 + t) * 28;
                float in[12];
                *(float4*)&in[0] = *(const float4*)(rp + co0);
                *(float4*)&in[4] = *(const float4*)(rp + co1);
                *(float4*)&in[8] = *(const float4*)(rp + co2);

                const int s0 = t % 3;
                const int s1 = (t + 2) % 3;
                const int s2 = (t + 1) % 3;

                if (t < RC) {
#pragma unroll
                    for (int j = 0; j < 8; ++j)
                        accr[s0][j] = fmaf(in[j], cw[0],
                                      fmaf(in[j + 1], cw[1],
                                      fmaf(in[j + 2], cw[2], accr[s0][j])));
                }
                if (t >= 1 && t <= RC) {
#pragma unroll
                    for (int j = 0; j < 8; ++j)
                        accr[s1][j] = fmaf(in[j], cw[3],
                                      fmaf(in[j + 1], cw[4],
                                      fmaf(in[j + 2], cw[5], accr[s1][j])));
                }
                if (t >= 2) {
#pragma unroll
                    for (int j = 0; j < 8; ++j)
                        accr[s2][j] = fmaf(in[j], cw[6],
                                      fmaf(in[j + 1], cw[7],
                                      fmaf(in[j + 2], cw[8], accr[s2][j])));
                    ABu a;
#pragma unroll
                    for (int m = 0; m < 4; ++m)
                        a.u[m] = pk_bf16(fmaxf(accr[s2][2 * m], 0.f),
                                         fmaxf(accr[s2][2 * m + 1], 0.f));
                    acc = __builtin_amdgcn_mfma_f32_16x16x32_bf16(
                              a.v, bf[t - 2].v, acc, 0, 0, 0);
#pragma unroll
                    for (int j = 0; j < 8; ++j) accr[s2][j] = 0.0f;
                }
            }
        }

        // ---- cross-wave K-reduction ----
        *reinterpret_cast<f32x4*>(scr + widb * 256 + lane * 4) = acc;
        asm volatile("s_waitcnt lgkmcnt(0)" ::: "memory");  // scratch visible
        __builtin_amdgcn_s_barrier();        // raw: DMA stays in flight
        __builtin_amdgcn_sched_barrier(0);

        if (widb == (i & 7)) {   // rotate reducer to spread barrier skew
            const float* sp = scr + lane * 4;
            float s[4] = {0.f, 0.f, 0.f, 0.f};
#pragma unroll
            for (int w = 0; w < NWAVES; ++w) {
                f32x4 p = *reinterpret_cast<const f32x4*>(sp + w * 256);
#pragma unroll
                for (int q = 0; q < 4; ++q) s[q] += p[q];
            }
            if (rc < 10) {
                float* po = out + ((size_t)grp * NIMG_GRP + (size_t)g * 4) * 10 + rc;
#pragma unroll
                for (int q = 0; q < 4; ++q) po[q * 10] = s[q] + bv;
            }
        }
    }
}

extern "C" void kernel_launch(void* const* d_in, const int* in_sizes, int n_in,
                              void* d_out, int out_size, void* d_ws, size_t ws_size,
                              hipStream_t stream) {
    const float* x   = (const float*)d_in[0];
    const float* cw  = (const float*)d_in[1];
    const float* W   = (const float*)d_in[2];
    const float* b   = (const float*)d_in[3];
    float* out = (float*)d_out;

    const int nimg    = in_sizes[0] / IMG_ELEMS;
    const int ngroups = nimg / NIMG_GRP;
    const int gpb     = (ngroups + BLOCKS - 1) / BLOCKS;  // 16 for B=65536

    hipLaunchKernelGGL(fused_digit_pipe_kernel, dim3(BLOCKS), dim3(512), 0, stream,
                       x, cw, W, b, out, ngroups, gpb);
}